// Round 5
// baseline (75.866 us; speedup 1.0000x reference)
//
#include <hip/hip_runtime.h>
#include <stdint.h>

#define NB    64       // batch
#define KMAX  16
#define VV    32000    // vocab
#define DVV   10
#define HH    4096
#define NROWS (NB*KMAX)
#define EPSF  1e-8f
#define NQ    8000     // float4 groups per row (4*8000 = 32000)
#define TOTELEM (NROWS*VV)            // 32768000
#define TGROUPS ((TOTELEM - 4) / 4)   // 8191999 full 16B-aligned output groups

// ---------------- Threefry-2x32 (exact JAX reference implementation) ----------------
__device__ __forceinline__ uint32_t rotl32(uint32_t v, int r) { return (v << r) | (v >> (32 - r)); }

__device__ __forceinline__ void tf2x32(uint32_t k0, uint32_t k1, uint32_t c0, uint32_t c1,
                                       uint32_t& o0, uint32_t& o1) {
    uint32_t ks2 = k0 ^ k1 ^ 0x1BD11BDAu;
    uint32_t x0 = c0 + k0, x1 = c1 + k1;
    const int RA[4] = {13, 15, 26, 6};
    const int RB[4] = {17, 29, 16, 24};
#pragma unroll
    for (int i = 0; i < 4; ++i) { x0 += x1; x1 = rotl32(x1, RA[i]); x1 ^= x0; }
    x0 += k1; x1 += ks2 + 1u;
#pragma unroll
    for (int i = 0; i < 4; ++i) { x0 += x1; x1 = rotl32(x1, RB[i]); x1 ^= x0; }
    x0 += ks2; x1 += k0 + 2u;
#pragma unroll
    for (int i = 0; i < 4; ++i) { x0 += x1; x1 = rotl32(x1, RA[i]); x1 ^= x0; }
    x0 += k0; x1 += k1 + 3u;
#pragma unroll
    for (int i = 0; i < 4; ++i) { x0 += x1; x1 = rotl32(x1, RB[i]); x1 ^= x0; }
    x0 += k1; x1 += ks2 + 4u;
#pragma unroll
    for (int i = 0; i < 4; ++i) { x0 += x1; x1 = rotl32(x1, RA[i]); x1 ^= x0; }
    x0 += ks2; x1 += k0 + 5u;
    o0 = x0; o1 = x1;
}

__device__ __forceinline__ float bits_to_u01(uint32_t bits) {
    uint32_t fb = (bits >> 9) | 0x3F800000u;
    return __uint_as_float(fb) - 1.0f;
}

// ------------- setup: reproduce JAX randoms, build per-row descriptors -------------
__global__ __launch_bounds__(1024) void setup_kernel(const int* __restrict__ k_vals,
                                                     int* __restrict__ src_arr,
                                                     float* __restrict__ itau_arr) {
    const int j = threadIdx.x;           // 0..1023
    const int b = j >> 4, s = j & 15;

    __shared__ float su[NROWS];
    __shared__ int   sk[NB];
    __shared__ int   sdp[NB];

    // split(key(0), 3): counts=[0..5]; out=[a0,a1,a2,b0,b1,b2] -> (3,2)
    uint32_t a0, b0, a1, b1, a2, b2;
    tf2x32(0u, 0u, 0u, 3u, a0, b0);
    tf2x32(0u, 0u, 1u, 4u, a1, b1);
    tf2x32(0u, 0u, 2u, 5u, a2, b2);
    const uint32_t kdec0 = a0, kdec1 = a1;
    const uint32_t kperm0 = a2, kperm1 = b0;
    const uint32_t ktau0 = b1, ktau1 = b2;

    // u_perm[j], tau[j]: size-1024 draws, counts split [0..511],[512..1023]
    uint32_t y0, y1, pb, tb;
    if (j < 512) { tf2x32(kperm0, kperm1, (uint32_t)j, (uint32_t)(j + 512), y0, y1); pb = y0; }
    else         { tf2x32(kperm0, kperm1, (uint32_t)(j - 512), (uint32_t)j, y0, y1); pb = y1; }
    su[j] = bits_to_u01(pb);
    if (j < 512) { tf2x32(ktau0, ktau1, (uint32_t)j, (uint32_t)(j + 512), y0, y1); tb = y0; }
    else         { tf2x32(ktau0, ktau1, (uint32_t)(j - 512), (uint32_t)j, y0, y1); tb = y1; }
    float tau = fmaxf(0.7f, bits_to_u01(tb) * 0.9f + 0.7f);
    float itau = 1.0f / tau;

    if (j < NB) {
        uint32_t bits;
        if (j < 32) { tf2x32(kdec0, kdec1, (uint32_t)j, (uint32_t)(j + 32), y0, y1); bits = y0; }
        else        { tf2x32(kdec0, kdec1, (uint32_t)(j - 32), (uint32_t)j, y0, y1); bits = y1; }
        float u_dec = bits_to_u01(bits);
        int k = k_vals[j];
        float prob = (k >= 2) ? 0.5f : 0.0f;
        sk[j] = k;
        sdp[j] = (k > 1) && (u_dec < prob);
    }
    __syncthreads();

    const int k = sk[b];
    const bool dp = sdp[b] != 0;
    const float INF = __int_as_float(0x7F800000);
    const float myk = (s < k) ? su[j] : INF;

    int r = 0;
#pragma unroll
    for (int t = 0; t < KMAX; ++t) {
        float kt = (t < k) ? su[(b << 4) + t] : INF;
        r += (kt < myk) || (kt == myk && t < s);
    }

    if (s >= k)      { src_arr[j] = s;            itau_arr[j] = 0.0f; }
    else if (dp)     { src_arr[(b << 4) + r] = s; itau_arr[(b << 4) + r] = 0.0f; }
    else             { src_arr[j] = -1;           itau_arr[j] = itau; }
}

// ------------- rowsum: normalizer for warp rows only -------------
__global__ __launch_bounds__(256) void rowsum_kernel(const float* __restrict__ p_z,
                                                     const int* __restrict__ src_arr,
                                                     const float* __restrict__ itau_arr,
                                                     float* __restrict__ scale_arr) {
    const int row = blockIdx.x;
    const int tid = threadIdx.x;
    if (src_arr[row] >= 0) { if (tid == 0) scale_arr[row] = 1.0f; return; }
    const float it = itau_arr[row];
    const float* s = p_z + (size_t)row * VV;
    float lsum = 0.f;
    for (int i = tid; i < NQ; i += 256) {
        float4 v = *(const float4*)(s + (i << 2));   // row base 16B-aligned
        lsum += exp2f(__log2f(fmaxf(v.x, EPSF)) * it)
              + exp2f(__log2f(fmaxf(v.y, EPSF)) * it)
              + exp2f(__log2f(fmaxf(v.z, EPSF)) * it)
              + exp2f(__log2f(fmaxf(v.w, EPSF)) * it);
    }
#pragma unroll
    for (int o = 32; o; o >>= 1) lsum += __shfl_down(lsum, o, 64);
    __shared__ float red[4];
    if ((tid & 63) == 0) red[tid >> 6] = lsum;
    __syncthreads();
    if (tid == 0) scale_arr[row] = 1.0f / (red[0] + red[1] + red[2] + red[3]);
}

// ------------- main: flat streaming build of p_cf_z -------------
__device__ __forceinline__ float cf_elem(const float* __restrict__ p_z,
                                         const int* __restrict__ src_arr,
                                         const float* __restrict__ itau_arr,
                                         const float* __restrict__ scale_arr,
                                         uint32_t row, uint32_t v) {
    int src = src_arr[row];
    if (src >= 0) return p_z[(size_t)((row & ~15u) + (uint32_t)src) * VV + v];
    float p = fmaxf(p_z[(size_t)row * VV + v], EPSF);
    return exp2f(__log2f(p) * itau_arr[row]) * scale_arr[row];
}

// One 16B output group per loop iteration: out elems e = 4t+1 .. 4t+4 live at
// o+3+e (byte 16+16t: aligned store). Loads are dword-aligned unaligned float4.
// Row-boundary groups (v0 == VV-3, 1 in 8000) gather per-element. No LDS, no
// syncs, 256-thread blocks -> max occupancy and outstanding-load depth.
__global__ __launch_bounds__(256) void cf_flat_kernel(const float* __restrict__ p_z,
                                                      const int* __restrict__ src_arr,
                                                      const float* __restrict__ itau_arr,
                                                      const float* __restrict__ scale_arr,
                                                      float* __restrict__ o /* d_out */) {
    const uint32_t stride = gridDim.x * blockDim.x;
    for (uint32_t t = blockIdx.x * blockDim.x + threadIdx.x; t < TGROUPS; t += stride) {
        const uint32_t e0 = 4u * t + 1u;
        const uint32_t row = e0 / VV;
        const uint32_t v0 = e0 - row * VV;     // ≡ 1 mod 4
        float4 stv;
        if (v0 != VV - 3) {                    // whole group inside `row`
            const int src = src_arr[row];
            if (src >= 0) {
                const float* s = p_z + (size_t)((row & ~15u) + (uint32_t)src) * VV + v0;
                stv = *(const float4*)s;
            } else {
                const float it = itau_arr[row];
                const float sc = scale_arr[row];
                const float* s = p_z + (size_t)row * VV + v0;
                float4 v = *(const float4*)s;
                stv.x = exp2f(__log2f(fmaxf(v.x, EPSF)) * it) * sc;
                stv.y = exp2f(__log2f(fmaxf(v.y, EPSF)) * it) * sc;
                stv.z = exp2f(__log2f(fmaxf(v.z, EPSF)) * it) * sc;
                stv.w = exp2f(__log2f(fmaxf(v.w, EPSF)) * it) * sc;
            }
        } else {                               // spans row boundary (never past last row)
            stv.x = cf_elem(p_z, src_arr, itau_arr, scale_arr, row, VV - 3);
            stv.y = cf_elem(p_z, src_arr, itau_arr, scale_arr, row, VV - 2);
            stv.z = cf_elem(p_z, src_arr, itau_arr, scale_arr, row, VV - 1);
            stv.w = cf_elem(p_z, src_arr, itau_arr, scale_arr, row + 1, 0);
        }
        *(float4*)(o + 3 + e0) = stv;
    }
    if (blockIdx.x == 0 && threadIdx.x == 0) {   // global edges
        o[3] = cf_elem(p_z, src_arr, itau_arr, scale_arr, 0, 0);
        o[3 + TOTELEM - 3] = cf_elem(p_z, src_arr, itau_arr, scale_arr, NROWS - 1, VV - 3);
        o[3 + TOTELEM - 2] = cf_elem(p_z, src_arr, itau_arr, scale_arr, NROWS - 1, VV - 2);
        o[3 + TOTELEM - 1] = cf_elem(p_z, src_arr, itau_arr, scale_arr, NROWS - 1, VV - 1);
    }
}

// ------------- per-batch reductions over h_ans (H=4096) -------------
__global__ __launch_bounds__(256) void rowred_kernel(const float* __restrict__ hr,
                                                     const float* __restrict__ hc,
                                                     float* __restrict__ cosb,
                                                     float* __restrict__ depb) {
    int b = blockIdx.x;
    const float4* r4 = (const float4*)(hr + (size_t)b * HH);
    const float4* c4 = (const float4*)(hc + (size_t)b * HH);
    float srr = 0.f, scc = 0.f, sxc = 0.f, sdd = 0.f;
    for (int i = threadIdx.x; i < HH / 4; i += 256) {
        float4 r = r4[i], c = c4[i];
        srr += r.x * r.x + r.y * r.y + r.z * r.z + r.w * r.w;
        scc += c.x * c.x + c.y * c.y + c.z * c.z + c.w * c.w;
        sxc += r.x * c.x + r.y * c.y + r.z * c.z + r.w * c.w;
        float dx = r.x - c.x, dy = r.y - c.y, dz = r.z - c.z, dw = r.w - c.w;
        sdd += dx * dx + dy * dy + dz * dz + dw * dw;
    }
#pragma unroll
    for (int o = 32; o; o >>= 1) {
        srr += __shfl_down(srr, o, 64);
        scc += __shfl_down(scc, o, 64);
        sxc += __shfl_down(sxc, o, 64);
        sdd += __shfl_down(sdd, o, 64);
    }
    __shared__ float red[4][4];
    int w = threadIdx.x >> 6;
    if ((threadIdx.x & 63) == 0) { red[w][0] = srr; red[w][1] = scc; red[w][2] = sxc; red[w][3] = sdd; }
    __syncthreads();
    if (threadIdx.x == 0) {
        float t0 = 0.f, t1 = 0.f, t2 = 0.f, t3 = 0.f;
        for (int i = 0; i < 4; ++i) { t0 += red[i][0]; t1 += red[i][1]; t2 += red[i][2]; t3 += red[i][3]; }
        float nr = fmaxf(sqrtf(t0), 1e-12f);
        float nc = fmaxf(sqrtf(t1), 1e-12f);
        cosb[b] = t2 / (nr * nc);
        depb[b] = sqrtf(t3);
    }
}

// ------------- JS divergence + final scalars -------------
__global__ void finalize_kernel(const float* __restrict__ dlr, const float* __restrict__ dlc,
                                const float* __restrict__ cosb, const float* __restrict__ depb,
                                float* __restrict__ out) {
    int b = threadIdx.x;  // 64 threads = 1 wave
    float lr[DVV], lc[DVV];
    float mr = -1e30f, mc = -1e30f;
#pragma unroll
    for (int v = 0; v < DVV; ++v) {
        lr[v] = dlr[b * DVV + v]; lc[v] = dlc[b * DVV + v];
        mr = fmaxf(mr, lr[v]); mc = fmaxf(mc, lc[v]);
    }
    float sr = 0.f, sc = 0.f;
#pragma unroll
    for (int v = 0; v < DVV; ++v) {
        lr[v] = expf(lr[v] - mr); sr += lr[v];
        lc[v] = expf(lc[v] - mc); sc += lc[v];
    }
    float js = 0.f;
#pragma unroll
    for (int v = 0; v < DVV; ++v) {
        float p = fmaxf(lr[v] / sr, EPSF);
        float q = fmaxf(lc[v] / sc, EPSF);
        float m = 0.5f * (p + q);
        float lm = logf(m);
        js += 0.5f * (p * (logf(p) - lm) + q * (logf(q) - lm));
    }
    float cs = cosb[b], dp = depb[b];
#pragma unroll
    for (int o = 32; o; o >>= 1) {
        js += __shfl_down(js, o, 64);
        cs += __shfl_down(cs, o, 64);
        dp += __shfl_down(dp, o, 64);
    }
    if (b == 0) {
        out[0] = logf(2.0f) - js * (1.0f / 64.0f);
        out[1] = cs * (1.0f / 64.0f) - 1.0f;
        out[2] = dp * (1.0f / 64.0f);
    }
}

extern "C" void kernel_launch(void* const* d_in, const int* in_sizes, int n_in,
                              void* d_out, int out_size, void* d_ws, size_t ws_size,
                              hipStream_t stream) {
    const float* p_z = (const float*)d_in[0];
    const float* dlr = (const float*)d_in[1];
    const float* dlc = (const float*)d_in[2];
    const float* hr  = (const float*)d_in[3];
    const float* hc  = (const float*)d_in[4];
    const int*   kv  = (const int*)d_in[5];
    float* out = (float*)d_out;

    int*   src_arr   = (int*)d_ws;
    float* itau_arr  = (float*)d_ws + NROWS;
    float* scale_arr = (float*)d_ws + 2 * NROWS;
    float* cosb      = (float*)d_ws + 3 * NROWS;
    float* depb      = cosb + NB;

    setup_kernel<<<1, 1024, 0, stream>>>(kv, src_arr, itau_arr);
    rowsum_kernel<<<NROWS, 256, 0, stream>>>(p_z, src_arr, itau_arr, scale_arr);
    cf_flat_kernel<<<4096, 256, 0, stream>>>(p_z, src_arr, itau_arr, scale_arr, out);
    rowred_kernel<<<NB, 256, 0, stream>>>(hr, hc, cosb, depb);
    finalize_kernel<<<1, 64, 0, stream>>>(dlr, dlc, cosb, depb, out);
}

// Round 6
// 64.727 us; speedup vs baseline: 1.1721x; 1.1721x over previous
//
#include <hip/hip_runtime.h>
#include <stdint.h>

#define NB    64       // batch
#define KMAX  16
#define VV    32000    // vocab
#define DVV   10
#define HH    4096
#define NROWS (NB*KMAX)
#define EPSF  1e-8f
#define NQ    8000     // float4 groups per row (4*8000 = 32000)

typedef float floatx4 __attribute__((ext_vector_type(4)));

// ---------------- Threefry-2x32 (exact JAX reference implementation) ----------------
__device__ __forceinline__ uint32_t rotl32(uint32_t v, int r) { return (v << r) | (v >> (32 - r)); }

__device__ __forceinline__ void tf2x32(uint32_t k0, uint32_t k1, uint32_t c0, uint32_t c1,
                                       uint32_t& o0, uint32_t& o1) {
    uint32_t ks2 = k0 ^ k1 ^ 0x1BD11BDAu;
    uint32_t x0 = c0 + k0, x1 = c1 + k1;
    const int RA[4] = {13, 15, 26, 6};
    const int RB[4] = {17, 29, 16, 24};
#pragma unroll
    for (int i = 0; i < 4; ++i) { x0 += x1; x1 = rotl32(x1, RA[i]); x1 ^= x0; }
    x0 += k1; x1 += ks2 + 1u;
#pragma unroll
    for (int i = 0; i < 4; ++i) { x0 += x1; x1 = rotl32(x1, RB[i]); x1 ^= x0; }
    x0 += ks2; x1 += k0 + 2u;
#pragma unroll
    for (int i = 0; i < 4; ++i) { x0 += x1; x1 = rotl32(x1, RA[i]); x1 ^= x0; }
    x0 += k0; x1 += k1 + 3u;
#pragma unroll
    for (int i = 0; i < 4; ++i) { x0 += x1; x1 = rotl32(x1, RB[i]); x1 ^= x0; }
    x0 += k1; x1 += ks2 + 4u;
#pragma unroll
    for (int i = 0; i < 4; ++i) { x0 += x1; x1 = rotl32(x1, RA[i]); x1 ^= x0; }
    x0 += ks2; x1 += k0 + 5u;
    o0 = x0; o1 = x1;
}

__device__ __forceinline__ float bits_to_u01(uint32_t bits) {
    uint32_t fb = (bits >> 9) | 0x3F800000u;
    return __uint_as_float(fb) - 1.0f;
}

__device__ __forceinline__ void nt_store4(float* p, float a, float b, float c, float d) {
    floatx4 v = {a, b, c, d};
    __builtin_nontemporal_store(v, (floatx4*)p);
}

// ------------- setup: reproduce JAX randoms, build per-row descriptors -------------
__global__ __launch_bounds__(1024) void setup_kernel(const int* __restrict__ k_vals,
                                                     int* __restrict__ src_arr,
                                                     float* __restrict__ itau_arr) {
    const int j = threadIdx.x;           // 0..1023
    const int b = j >> 4, s = j & 15;

    __shared__ float su[NROWS];
    __shared__ int   sk[NB];
    __shared__ int   sdp[NB];

    // split(key(0), 3): counts=[0..5]; out=[a0,a1,a2,b0,b1,b2] -> (3,2)
    uint32_t a0, b0, a1, b1, a2, b2;
    tf2x32(0u, 0u, 0u, 3u, a0, b0);
    tf2x32(0u, 0u, 1u, 4u, a1, b1);
    tf2x32(0u, 0u, 2u, 5u, a2, b2);
    const uint32_t kdec0 = a0, kdec1 = a1;
    const uint32_t kperm0 = a2, kperm1 = b0;
    const uint32_t ktau0 = b1, ktau1 = b2;

    // u_perm[j], tau[j]: size-1024 draws, counts split [0..511],[512..1023]
    uint32_t y0, y1, pb, tb;
    if (j < 512) { tf2x32(kperm0, kperm1, (uint32_t)j, (uint32_t)(j + 512), y0, y1); pb = y0; }
    else         { tf2x32(kperm0, kperm1, (uint32_t)(j - 512), (uint32_t)j, y0, y1); pb = y1; }
    su[j] = bits_to_u01(pb);
    if (j < 512) { tf2x32(ktau0, ktau1, (uint32_t)j, (uint32_t)(j + 512), y0, y1); tb = y0; }
    else         { tf2x32(ktau0, ktau1, (uint32_t)(j - 512), (uint32_t)j, y0, y1); tb = y1; }
    float tau = fmaxf(0.7f, bits_to_u01(tb) * 0.9f + 0.7f);
    float itau = 1.0f / tau;

    if (j < NB) {
        uint32_t bits;
        if (j < 32) { tf2x32(kdec0, kdec1, (uint32_t)j, (uint32_t)(j + 32), y0, y1); bits = y0; }
        else        { tf2x32(kdec0, kdec1, (uint32_t)(j - 32), (uint32_t)j, y0, y1); bits = y1; }
        float u_dec = bits_to_u01(bits);
        int k = k_vals[j];
        float prob = (k >= 2) ? 0.5f : 0.0f;
        sk[j] = k;
        sdp[j] = (k > 1) && (u_dec < prob);
    }
    __syncthreads();

    const int k = sk[b];
    const bool dp = sdp[b] != 0;
    const float INF = __int_as_float(0x7F800000);
    const float myk = (s < k) ? su[j] : INF;

    int r = 0;
#pragma unroll
    for (int t = 0; t < KMAX; ++t) {
        float kt = (t < k) ? su[(b << 4) + t] : INF;
        r += (kt < myk) || (kt == myk && t < s);
    }

    if (s >= k)      { src_arr[j] = s;            itau_arr[j] = 0.0f; }
    else if (dp)     { src_arr[(b << 4) + r] = s; itau_arr[(b << 4) + r] = 0.0f; }
    else             { src_arr[j] = -1;           itau_arr[j] = itau; }
}

// ------------- per-batch reductions over h_ans (H=4096) -------------
__global__ __launch_bounds__(256) void rowred_kernel(const float* __restrict__ hr,
                                                     const float* __restrict__ hc,
                                                     float* __restrict__ cosb,
                                                     float* __restrict__ depb) {
    int b = blockIdx.x;
    const float4* r4 = (const float4*)(hr + (size_t)b * HH);
    const float4* c4 = (const float4*)(hc + (size_t)b * HH);
    float srr = 0.f, scc = 0.f, sxc = 0.f, sdd = 0.f;
    for (int i = threadIdx.x; i < HH / 4; i += 256) {
        float4 r = r4[i], c = c4[i];
        srr += r.x * r.x + r.y * r.y + r.z * r.z + r.w * r.w;
        scc += c.x * c.x + c.y * c.y + c.z * c.z + c.w * c.w;
        sxc += r.x * c.x + r.y * c.y + r.z * c.z + r.w * c.w;
        float dx = r.x - c.x, dy = r.y - c.y, dz = r.z - c.z, dw = r.w - c.w;
        sdd += dx * dx + dy * dy + dz * dz + dw * dw;
    }
#pragma unroll
    for (int o = 32; o; o >>= 1) {
        srr += __shfl_down(srr, o, 64);
        scc += __shfl_down(scc, o, 64);
        sxc += __shfl_down(sxc, o, 64);
        sdd += __shfl_down(sdd, o, 64);
    }
    __shared__ float red[4][4];
    int w = threadIdx.x >> 6;
    if ((threadIdx.x & 63) == 0) { red[w][0] = srr; red[w][1] = scc; red[w][2] = sxc; red[w][3] = sdd; }
    __syncthreads();
    if (threadIdx.x == 0) {
        float t0 = 0.f, t1 = 0.f, t2 = 0.f, t3 = 0.f;
        for (int i = 0; i < 4; ++i) { t0 += red[i][0]; t1 += red[i][1]; t2 += red[i][2]; t3 += red[i][3]; }
        float nr = fmaxf(sqrtf(t0), 1e-12f);
        float nc = fmaxf(sqrtf(t1), 1e-12f);
        cosb[b] = t2 / (nr * nc);
        depb[b] = sqrtf(t3);
    }
}

// ------------- JS divergence + final scalars -------------
__global__ void finalize_kernel(const float* __restrict__ dlr, const float* __restrict__ dlc,
                                const float* __restrict__ cosb, const float* __restrict__ depb,
                                float* __restrict__ out) {
    int b = threadIdx.x;  // 64 threads = 1 wave
    float lr[DVV], lc[DVV];
    float mr = -1e30f, mc = -1e30f;
#pragma unroll
    for (int v = 0; v < DVV; ++v) {
        lr[v] = dlr[b * DVV + v]; lc[v] = dlc[b * DVV + v];
        mr = fmaxf(mr, lr[v]); mc = fmaxf(mc, lc[v]);
    }
    float sr = 0.f, sc = 0.f;
#pragma unroll
    for (int v = 0; v < DVV; ++v) {
        lr[v] = expf(lr[v] - mr); sr += lr[v];
        lc[v] = expf(lc[v] - mc); sc += lc[v];
    }
    float js = 0.f;
#pragma unroll
    for (int v = 0; v < DVV; ++v) {
        float p = fmaxf(lr[v] / sr, EPSF);
        float q = fmaxf(lc[v] / sc, EPSF);
        float m = 0.5f * (p + q);
        float lm = logf(m);
        js += 0.5f * (p * (logf(p) - lm) + q * (logf(q) - lm));
    }
    float cs = cosb[b], dp = depb[b];
#pragma unroll
    for (int o = 32; o; o >>= 1) {
        js += __shfl_down(js, o, 64);
        cs += __shfl_down(cs, o, 64);
        dp += __shfl_down(dp, o, 64);
    }
    if (b == 0) {
        out[0] = logf(2.0f) - js * (1.0f / 64.0f);
        out[1] = cs * (1.0f / 64.0f) - 1.0f;
        out[2] = dp * (1.0f / 64.0f);
    }
}

// ------------- main: build p_cf_z (one block per row) -------------
// dst row base ≡ 3 mod 4 floats. Stores are 16B-aligned at dst+4q+1; loads are
// dword-aligned unaligned float4 of the same span. Warp path is TWO-PASS:
// pass 1 computes the power-sum with aligned loads (no register cache -> no
// scratch spill; R4's float4 r[8] spilled at VGPR=28), pass 2 re-reads the row
// (128 KB, L2-resident) and stores. Edges handled once by threads 0/1.
__global__ __launch_bounds__(1024) void cf_main_kernel(const float* __restrict__ p_z,
                                                       const int* __restrict__ src_arr,
                                                       const float* __restrict__ itau_arr,
                                                       float* __restrict__ out) {
    const int row = blockIdx.x;
    const int b = row >> 4;
    const int src = src_arr[row];
    const int tid = threadIdx.x;
    float* dst = out + (size_t)row * VV;

    if (src >= 0) {  // copy (self or permuted slot): one read, one NT write
        const float* s = p_z + ((size_t)((b << 4) + src)) * VV;
#pragma unroll
        for (int i = 0; i < 8; ++i) {
            const int q = tid + (i << 10);
            if (q < NQ - 1) {
                float4 v = *(const float4*)(s + (q << 2) + 1);
                nt_store4(dst + (q << 2) + 1, v.x, v.y, v.z, v.w);
            }
        }
        if (tid == 0) dst[0] = s[0];
        if (tid == 1) {
            dst[VV - 3] = s[VV - 3];
            dst[VV - 2] = s[VV - 2];
            dst[VV - 1] = s[VV - 1];
        }
        return;
    }

    // temperature warp: p^(1/tau) / sum(p^(1/tau))
    const float it = itau_arr[row];
    const float* s = p_z + (size_t)row * VV;

    // pass 1: power-sum over the whole row (aligned float4 loads)
    float lsum = 0.f;
#pragma unroll
    for (int i = 0; i < 8; ++i) {
        const int q = tid + (i << 10);
        if (q < NQ) {
            float4 v = *(const float4*)(s + (q << 2));
            lsum += exp2f(__log2f(fmaxf(v.x, EPSF)) * it)
                  + exp2f(__log2f(fmaxf(v.y, EPSF)) * it)
                  + exp2f(__log2f(fmaxf(v.z, EPSF)) * it)
                  + exp2f(__log2f(fmaxf(v.w, EPSF)) * it);
        }
    }
    // block reduce (16 waves)
    __shared__ float red[16];
    float t = lsum;
#pragma unroll
    for (int o = 32; o; o >>= 1) t += __shfl_down(t, o, 64);
    if ((tid & 63) == 0) red[tid >> 6] = t;
    __syncthreads();
    if (tid < 64) {
        float u = (tid < 16) ? red[tid] : 0.0f;
#pragma unroll
        for (int o = 8; o; o >>= 1) u += __shfl_down(u, o, 64);
        if (tid == 0) red[0] = u;
    }
    __syncthreads();
    const float scale = 1.0f / red[0];

    // pass 2: re-read (L2-hot), transform, store aligned spans
#pragma unroll
    for (int i = 0; i < 8; ++i) {
        const int q = tid + (i << 10);
        if (q < NQ - 1) {
            float4 v = *(const float4*)(s + (q << 2) + 1);
            nt_store4(dst + (q << 2) + 1,
                      exp2f(__log2f(fmaxf(v.x, EPSF)) * it) * scale,
                      exp2f(__log2f(fmaxf(v.y, EPSF)) * it) * scale,
                      exp2f(__log2f(fmaxf(v.z, EPSF)) * it) * scale,
                      exp2f(__log2f(fmaxf(v.w, EPSF)) * it) * scale);
        }
    }
    if (tid == 0) dst[0] = exp2f(__log2f(fmaxf(s[0], EPSF)) * it) * scale;
    if (tid == 1) {
        dst[VV - 3] = exp2f(__log2f(fmaxf(s[VV - 3], EPSF)) * it) * scale;
        dst[VV - 2] = exp2f(__log2f(fmaxf(s[VV - 2], EPSF)) * it) * scale;
        dst[VV - 1] = exp2f(__log2f(fmaxf(s[VV - 1], EPSF)) * it) * scale;
    }
}

extern "C" void kernel_launch(void* const* d_in, const int* in_sizes, int n_in,
                              void* d_out, int out_size, void* d_ws, size_t ws_size,
                              hipStream_t stream) {
    const float* p_z = (const float*)d_in[0];
    const float* dlr = (const float*)d_in[1];
    const float* dlc = (const float*)d_in[2];
    const float* hr  = (const float*)d_in[3];
    const float* hc  = (const float*)d_in[4];
    const int*   kv  = (const int*)d_in[5];
    float* out = (float*)d_out;

    int*   src_arr  = (int*)d_ws;
    float* itau_arr = (float*)d_ws + NROWS;
    float* cosb     = (float*)d_ws + 2 * NROWS;
    float* depb     = cosb + NB;

    setup_kernel<<<1, 1024, 0, stream>>>(kv, src_arr, itau_arr);
    cf_main_kernel<<<NROWS, 1024, 0, stream>>>(p_z, src_arr, itau_arr, out + 3);
    rowred_kernel<<<NB, 256, 0, stream>>>(hr, hc, cosb, depb);
    finalize_kernel<<<1, 64, 0, stream>>>(dlr, dlc, cosb, depb, out);
}

// Round 7
// 57.969 us; speedup vs baseline: 1.3088x; 1.1166x over previous
//
#include <hip/hip_runtime.h>
#include <stdint.h>

#define NB    64       // batch
#define KMAX  16
#define VV    32000    // vocab
#define DVV   10
#define HH    4096
#define NROWS (NB*KMAX)
#define EPSF  1e-8f
#define NQ    8000     // float4 groups per row (4*8000 = 32000)

// ---------------- Threefry-2x32 (exact JAX reference implementation) ----------------
__device__ __forceinline__ uint32_t rotl32(uint32_t v, int r) { return (v << r) | (v >> (32 - r)); }

__device__ __forceinline__ void tf2x32(uint32_t k0, uint32_t k1, uint32_t c0, uint32_t c1,
                                       uint32_t& o0, uint32_t& o1) {
    uint32_t ks2 = k0 ^ k1 ^ 0x1BD11BDAu;
    uint32_t x0 = c0 + k0, x1 = c1 + k1;
    const int RA[4] = {13, 15, 26, 6};
    const int RB[4] = {17, 29, 16, 24};
#pragma unroll
    for (int i = 0; i < 4; ++i) { x0 += x1; x1 = rotl32(x1, RA[i]); x1 ^= x0; }
    x0 += k1; x1 += ks2 + 1u;
#pragma unroll
    for (int i = 0; i < 4; ++i) { x0 += x1; x1 = rotl32(x1, RB[i]); x1 ^= x0; }
    x0 += ks2; x1 += k0 + 2u;
#pragma unroll
    for (int i = 0; i < 4; ++i) { x0 += x1; x1 = rotl32(x1, RA[i]); x1 ^= x0; }
    x0 += k0; x1 += k1 + 3u;
#pragma unroll
    for (int i = 0; i < 4; ++i) { x0 += x1; x1 = rotl32(x1, RB[i]); x1 ^= x0; }
    x0 += k1; x1 += ks2 + 4u;
#pragma unroll
    for (int i = 0; i < 4; ++i) { x0 += x1; x1 = rotl32(x1, RA[i]); x1 ^= x0; }
    x0 += ks2; x1 += k0 + 5u;
    o0 = x0; o1 = x1;
}

__device__ __forceinline__ float bits_to_u01(uint32_t bits) {
    uint32_t fb = (bits >> 9) | 0x3F800000u;
    return __uint_as_float(fb) - 1.0f;
}

// ------------- main: build p_cf_z (one block per row, setup fused) -------------
// Row descriptor (src slot or 1/tau) is derived in-block by the first 16 lanes:
// lane t computes u_perm for batch slot t, stable rank r via 16-lane shfl
// compare (inactive->+inf, ties by index; inactive lanes get r==t), and the
// lane whose r matches this row's slot s resolves the inverse permutation.
// dst row base ≡ 3 mod 4 floats: stores are 16B-aligned at dst+4q+1, loads are
// dword-aligned unaligned float4 of the same span. Warp rows cache the row in
// r[8] float4 regs (unified VGPR/AGPR file) -> one read, one write.
__global__ __launch_bounds__(1024) void cf_main_kernel(const float* __restrict__ p_z,
                                                       const int* __restrict__ k_vals,
                                                       float* __restrict__ out) {
    const int row = blockIdx.x;
    const int b = row >> 4, s = row & 15;
    const int tid = threadIdx.x;
    float* dst = out + (size_t)row * VV;

    __shared__ int   s_src;
    __shared__ float s_itau;

    if (tid < 16) {
        const int t = tid;
        // split(key(0), 3): counts=[0..5]; out=[a0,a1,a2,b0,b1,b2] -> (3,2)
        uint32_t a0, b0_, a1, b1_, a2, b2_, y0, y1;
        tf2x32(0u, 0u, 0u, 3u, a0, b0_);
        tf2x32(0u, 0u, 1u, 4u, a1, b1_);
        tf2x32(0u, 0u, 2u, 5u, a2, b2_);
        const uint32_t kdec0 = a0, kdec1 = a1;
        const uint32_t kperm0 = a2, kperm1 = b0_;
        const uint32_t ktau0 = b1_, ktau1 = b2_;

        const int k = k_vals[b];

        // u_dec for this batch (size-64 draw, counts split [0..31],[32..63])
        uint32_t bits;
        if (b < 32) { tf2x32(kdec0, kdec1, (uint32_t)b, (uint32_t)(b + 32), y0, y1); bits = y0; }
        else        { tf2x32(kdec0, kdec1, (uint32_t)(b - 32), (uint32_t)b, y0, y1); bits = y1; }
        const float u_dec = bits_to_u01(bits);
        const bool dp = (k > 1) && (u_dec < ((k >= 2) ? 0.5f : 0.0f));

        // u_perm for batch slot t (size-1024 draw, counts split [0..511],[512..1023])
        const int j = (b << 4) + t;
        uint32_t pb;
        if (j < 512) { tf2x32(kperm0, kperm1, (uint32_t)j, (uint32_t)(j + 512), y0, y1); pb = y0; }
        else         { tf2x32(kperm0, kperm1, (uint32_t)(j - 512), (uint32_t)j, y0, y1); pb = y1; }
        const float up = bits_to_u01(pb);

        const float INF = __int_as_float(0x7F800000);
        const float keyt = (t < k) ? up : INF;
        int r = 0;
#pragma unroll
        for (int tt = 0; tt < KMAX; ++tt) {
            float kt = __shfl(keyt, tt, 64);
            r += (kt < keyt) || (kt == keyt && tt < t);
        }

        if (s >= k)  { if (t == 0) { s_src = s; s_itau = 0.f; } }    // inactive: self-copy
        else if (dp) { if (r == s) { s_src = t; s_itau = 0.f; } }    // permuted: inverse perm
        else if (t == 0) {                                            // warp: tau for (b,s)
            const int js = (b << 4) + s;
            uint32_t tb;
            if (js < 512) { tf2x32(ktau0, ktau1, (uint32_t)js, (uint32_t)(js + 512), y0, y1); tb = y0; }
            else          { tf2x32(ktau0, ktau1, (uint32_t)(js - 512), (uint32_t)js, y0, y1); tb = y1; }
            const float tau = fmaxf(0.7f, bits_to_u01(tb) * 0.9f + 0.7f);
            s_src = -1; s_itau = 1.0f / tau;
        }
    }
    __syncthreads();

    const int src = s_src;

    if (src >= 0) {  // copy (self or permuted slot): one read, one write
        const float* sp = p_z + ((size_t)((b << 4) + src)) * VV;
#pragma unroll
        for (int i = 0; i < 8; ++i) {
            const int q = tid + (i << 10);
            if (q < NQ - 1) {
                float4 v = *(const float4*)(sp + (q << 2) + 1);
                *(float4*)(dst + (q << 2) + 1) = v;
            }
        }
        if (tid == 0) dst[0] = sp[0];
        if (tid == 1) {
            dst[VV - 3] = sp[VV - 3];
            dst[VV - 2] = sp[VV - 2];
            dst[VV - 1] = sp[VV - 1];
        }
        return;
    }

    // temperature warp: p^(1/tau) / sum(p^(1/tau)); row cached in registers.
    const float it = s_itau;
    const float* sp = p_z + (size_t)row * VV;
    float4 r[8];
    float e0 = 0.f, t0 = 0.f, t1 = 0.f, t2 = 0.f;
    float lsum = 0.f;
#pragma unroll
    for (int i = 0; i < 8; ++i) {
        const int q = tid + (i << 10);
        if (q < NQ - 1) {
            float4 v = *(const float4*)(sp + (q << 2) + 1);
            v.x = exp2f(__log2f(fmaxf(v.x, EPSF)) * it);
            v.y = exp2f(__log2f(fmaxf(v.y, EPSF)) * it);
            v.z = exp2f(__log2f(fmaxf(v.z, EPSF)) * it);
            v.w = exp2f(__log2f(fmaxf(v.w, EPSF)) * it);
            r[i] = v;
            lsum += v.x + v.y + v.z + v.w;
        } else {
            r[i] = make_float4(0.f, 0.f, 0.f, 0.f);
        }
    }
    if (tid == 0) { e0 = exp2f(__log2f(fmaxf(sp[0], EPSF)) * it); lsum += e0; }
    if (tid == 1) {
        t0 = exp2f(__log2f(fmaxf(sp[VV - 3], EPSF)) * it);
        t1 = exp2f(__log2f(fmaxf(sp[VV - 2], EPSF)) * it);
        t2 = exp2f(__log2f(fmaxf(sp[VV - 1], EPSF)) * it);
        lsum += t0 + t1 + t2;
    }
    // block reduce (16 waves)
    __shared__ float red[16];
    float t = lsum;
#pragma unroll
    for (int o = 32; o; o >>= 1) t += __shfl_down(t, o, 64);
    if ((tid & 63) == 0) red[tid >> 6] = t;
    __syncthreads();
    if (tid < 64) {
        float u = (tid < 16) ? red[tid] : 0.0f;
#pragma unroll
        for (int o = 8; o; o >>= 1) u += __shfl_down(u, o, 64);
        if (tid == 0) red[0] = u;
    }
    __syncthreads();
    const float scale = 1.0f / red[0];

#pragma unroll
    for (int i = 0; i < 8; ++i) {
        const int q = tid + (i << 10);
        if (q < NQ - 1) {
            float4 st;
            st.x = r[i].x * scale; st.y = r[i].y * scale;
            st.z = r[i].z * scale; st.w = r[i].w * scale;
            *(float4*)(dst + (q << 2) + 1) = st;
        }
    }
    if (tid == 0) dst[0] = e0 * scale;
    if (tid == 1) {
        dst[VV - 3] = t0 * scale;
        dst[VV - 2] = t1 * scale;
        dst[VV - 1] = t2 * scale;
    }
}

// ------------- per-batch reductions over h_ans (H=4096) -------------
__global__ __launch_bounds__(256) void rowred_kernel(const float* __restrict__ hr,
                                                     const float* __restrict__ hc,
                                                     float* __restrict__ cosb,
                                                     float* __restrict__ depb) {
    int b = blockIdx.x;
    const float4* r4 = (const float4*)(hr + (size_t)b * HH);
    const float4* c4 = (const float4*)(hc + (size_t)b * HH);
    float srr = 0.f, scc = 0.f, sxc = 0.f, sdd = 0.f;
    for (int i = threadIdx.x; i < HH / 4; i += 256) {
        float4 r = r4[i], c = c4[i];
        srr += r.x * r.x + r.y * r.y + r.z * r.z + r.w * r.w;
        scc += c.x * c.x + c.y * c.y + c.z * c.z + c.w * c.w;
        sxc += r.x * c.x + r.y * c.y + r.z * c.z + r.w * c.w;
        float dx = r.x - c.x, dy = r.y - c.y, dz = r.z - c.z, dw = r.w - c.w;
        sdd += dx * dx + dy * dy + dz * dz + dw * dw;
    }
#pragma unroll
    for (int o = 32; o; o >>= 1) {
        srr += __shfl_down(srr, o, 64);
        scc += __shfl_down(scc, o, 64);
        sxc += __shfl_down(sxc, o, 64);
        sdd += __shfl_down(sdd, o, 64);
    }
    __shared__ float red[4][4];
    int w = threadIdx.x >> 6;
    if ((threadIdx.x & 63) == 0) { red[w][0] = srr; red[w][1] = scc; red[w][2] = sxc; red[w][3] = sdd; }
    __syncthreads();
    if (threadIdx.x == 0) {
        float t0 = 0.f, t1 = 0.f, t2 = 0.f, t3 = 0.f;
        for (int i = 0; i < 4; ++i) { t0 += red[i][0]; t1 += red[i][1]; t2 += red[i][2]; t3 += red[i][3]; }
        float nr = fmaxf(sqrtf(t0), 1e-12f);
        float nc = fmaxf(sqrtf(t1), 1e-12f);
        cosb[b] = t2 / (nr * nc);
        depb[b] = sqrtf(t3);
    }
}

// ------------- JS divergence + final scalars -------------
__global__ void finalize_kernel(const float* __restrict__ dlr, const float* __restrict__ dlc,
                                const float* __restrict__ cosb, const float* __restrict__ depb,
                                float* __restrict__ out) {
    int b = threadIdx.x;  // 64 threads = 1 wave
    float lr[DVV], lc[DVV];
    float mr = -1e30f, mc = -1e30f;
#pragma unroll
    for (int v = 0; v < DVV; ++v) {
        lr[v] = dlr[b * DVV + v]; lc[v] = dlc[b * DVV + v];
        mr = fmaxf(mr, lr[v]); mc = fmaxf(mc, lc[v]);
    }
    float sr = 0.f, sc = 0.f;
#pragma unroll
    for (int v = 0; v < DVV; ++v) {
        lr[v] = expf(lr[v] - mr); sr += lr[v];
        lc[v] = expf(lc[v] - mc); sc += lc[v];
    }
    float js = 0.f;
#pragma unroll
    for (int v = 0; v < DVV; ++v) {
        float p = fmaxf(lr[v] / sr, EPSF);
        float q = fmaxf(lc[v] / sc, EPSF);
        float m = 0.5f * (p + q);
        float lm = logf(m);
        js += 0.5f * (p * (logf(p) - lm) + q * (logf(q) - lm));
    }
    float cs = cosb[b], dp = depb[b];
#pragma unroll
    for (int o = 32; o; o >>= 1) {
        js += __shfl_down(js, o, 64);
        cs += __shfl_down(cs, o, 64);
        dp += __shfl_down(dp, o, 64);
    }
    if (b == 0) {
        out[0] = logf(2.0f) - js * (1.0f / 64.0f);
        out[1] = cs * (1.0f / 64.0f) - 1.0f;
        out[2] = dp * (1.0f / 64.0f);
    }
}

extern "C" void kernel_launch(void* const* d_in, const int* in_sizes, int n_in,
                              void* d_out, int out_size, void* d_ws, size_t ws_size,
                              hipStream_t stream) {
    const float* p_z = (const float*)d_in[0];
    const float* dlr = (const float*)d_in[1];
    const float* dlc = (const float*)d_in[2];
    const float* hr  = (const float*)d_in[3];
    const float* hc  = (const float*)d_in[4];
    const int*   kv  = (const int*)d_in[5];
    float* out = (float*)d_out;

    float* cosb = (float*)d_ws;
    float* depb = cosb + NB;

    cf_main_kernel<<<NROWS, 1024, 0, stream>>>(p_z, kv, out + 3);
    rowred_kernel<<<NB, 256, 0, stream>>>(hr, hc, cosb, depb);
    finalize_kernel<<<1, 64, 0, stream>>>(dlr, dlc, cosb, depb, out);
}